// Round 6
// baseline (20.742 us; speedup 1.0000x reference)
//
#include <hip/hip_runtime.h>

// VQ argmin: for each weight w[i], indices[i] = argmin_k (w[i] - cb[k])^2,
// first-index tie-break (matches jnp.argmin).
//
// Evidence so far:
//  - One launch only: per-launch floor ~14-16 us, launches don't pipeline
//    (R0 42/1L, R3 16.3/1L, R4 44.6/3L, R5 20.7/1L).
//  - d_ws untouchable: poison-fill (256 MiB, ~39 us) serializes into the
//    timed path when ws is used (R2).
//  - R3's shape (256 blocks x 1024 thr, 1 cb entry/thread, 1 hist atomic +
//    1 scatter atomic) beat R5's (1024 x 256, 4 entries/thread): 16.3 vs 20.7.
// This round = R3 shape + R5's fixed grid (kills R3's serial t==0 min/max
// reduce + 1 barrier) + finer buckets (NB=384) + tighter prune slack (w/8
// instead of a full bucket) so most lanes stop after 1-2 buckets.
//
// Exactness (distribution-independent; grid choice affects speed only):
//  - dist computed exactly as reference: fl(fl(x-c)^2); fl is monotone.
//  - Bucket bounds: values in buckets <= dl are <= GLO+(dl+1)*w + eps_assign
//    (eps_assign ~ few ulps of 4.2, < 1e-6). Prune edge adds w/8 = 2.7e-3
//    of slack, >> eps_assign, and prunes only when fl(gap^2) > best STRICTLY.
//    If some entry v beyond the edge tied best, then computed gap <= fl(x-v)
//    => fl(gap^2) <= dist(v) = best => no prune. No tie is ever skipped.
//    Symmetric argument on the right. Clamped out-of-range entries land in
//    end buckets and only loosen the bounds in the safe direction.
//  - best starts at +inf, so pruning cannot fire before at least one real
//    candidate is seen (gap^2 > inf is false) -> degenerate codebooks fine.
//  - Surviving candidates use explicit (d, original_index) lexicographic
//    compare -> atomic scatter order irrelevant; jnp.argmin first-index
//    tie-break exact.
//  - NaN x: cvt->0 bucket, nothing accepted, prune never fires, sentinel->0
//    == np.argmin of an all-NaN row.

#define N_W  262144
#define K_CB 1024
#define NB   384
#define BLK  1024
#define GRID (N_W / BLK)        // 256 blocks, 1/CU

#define GLO    (-4.2f)
#define GRANGE (8.4f)

__device__ __forceinline__ float dsq(float x, float c) {
    // Must match reference numerics exactly: subtract then square, fp32 RN.
    float d = x - c;
    return d * d;
}

__global__ __launch_bounds__(BLK) void vq_grid_kernel(
    const float* __restrict__ w,
    const float* __restrict__ cb,
    const int* __restrict__ y,
    int* __restrict__ out)
{
    __shared__ float bval[K_CB];      // bucketed codebook values
    __shared__ int   bidx[K_CB];      // their original indices
    __shared__ int   hist[NB];
    __shared__ int   bstart[NB + 1];
    __shared__ int   cursor[NB];

    const int t   = threadIdx.x;           // 0..1023
    const int gid = blockIdx.x * BLK + t;  // exact cover of N_W

    const float inv = (float)NB / GRANGE;
    const float wdt = GRANGE / (float)NB;

    // Global loads issued up front; latency hides under hist zeroing + B1.
    float x = w[gid];
    float c = cb[t];                        // one entry per thread

    if (t < NB) hist[t] = 0;
    __syncthreads();                                   // B1

    // ---- histogram (1 atomic/thread) ----
    int bb = min(max((int)((c - GLO) * inv), 0), NB - 1);
    atomicAdd(&hist[bb], 1);
    __syncthreads();                                   // B2

    // ---- exclusive prefix over 384 buckets (wave 0; 6 buckets/lane) ----
    if (t < 64) {
        int h[6], s[6];
        int run = 0;
        #pragma unroll
        for (int k = 0; k < 6; ++k) {
            h[k] = hist[6 * t + k];
            s[k] = run;              // prefix within this lane's 6 buckets
            run += h[k];
        }
        int inc = run;               // inclusive scan of per-lane totals
        #pragma unroll
        for (int off = 1; off < 64; off <<= 1) {
            int v = __shfl_up(inc, off);
            if (t >= off) inc += v;
        }
        int exc = inc - run;
        #pragma unroll
        for (int k = 0; k < 6; ++k) {
            bstart[6 * t + k] = exc + s[k];
            cursor[6 * t + k] = exc + s[k];
        }
        if (t == 63) bstart[NB] = inc;   // == K_CB
    }
    __syncthreads();                                   // B3

    // ---- scatter (value, original index) into bucket slots ----
    {
        int p = atomicAdd(&cursor[bb], 1);
        bval[p] = c;
        bidx[p] = t;
    }
    __syncthreads();                                   // B4

    // ---- query ----
    int b = min(max((int)((x - GLO) * inv), 0), NB - 1);

    float best = __builtin_inff();
    int   bi   = 0x7fffffff;

    {   // own bucket
        int e = bstart[b + 1];
        for (int i = bstart[b]; i < e; ++i) {
            float d = dsq(x, bval[i]);
            int idx = bidx[i];
            if (d < best)                   { best = d; bi = idx; }
            else if (d == best && idx < bi) { bi = idx; }
        }
    }

    int  dl = b - 1, dr = b + 1;
    bool goL = (dl >= 0);
    bool goR = (dr < NB);
    while (goL || goR) {
        if (goL) {
            // upper bound on values in buckets <= dl, slack w/8
            float edge = GLO + ((float)(dl + 1) + 0.125f) * wdt;
            float gap  = x - edge;
            if (gap > 0.0f && gap * gap > best) {
                goL = false;
            } else {
                int e = bstart[dl + 1];
                for (int i = bstart[dl]; i < e; ++i) {
                    float d = dsq(x, bval[i]);
                    int idx = bidx[i];
                    if (d < best)                   { best = d; bi = idx; }
                    else if (d == best && idx < bi) { bi = idx; }
                }
                if (--dl < 0) goL = false;
            }
        }
        if (goR) {
            // lower bound on values in buckets >= dr, slack w/8
            float edge = GLO + ((float)dr - 0.125f) * wdt;
            float gap  = edge - x;
            if (gap > 0.0f && gap * gap > best) {
                goR = false;
            } else {
                int e = bstart[dr + 1];
                for (int i = bstart[dr]; i < e; ++i) {
                    float d = dsq(x, bval[i]);
                    int idx = bidx[i];
                    if (d < best)                   { best = d; bi = idx; }
                    else if (d == best && idx < bi) { bi = idx; }
                }
                if (++dr >= NB) goR = false;
            }
        }
    }
    if (bi == 0x7fffffff) bi = 0;   // NaN-x: matches np.argmin on all-NaN row
    out[gid] = bi;

    if (gid == 0) out[N_W] = y[0];
}

extern "C" void kernel_launch(void* const* d_in, const int* in_sizes, int n_in,
                              void* d_out, int out_size, void* d_ws, size_t ws_size,
                              hipStream_t stream) {
    const float* w  = (const float*)d_in[0];
    const float* cb = (const float*)d_in[1]; // (K,1) contiguous == K floats
    const int*   y  = (const int*)d_in[2];
    int* out = (int*)d_out;

    // ONE launch (per-launch overhead ~14-16 us, launches don't pipeline);
    // d_ws untouched (poison-fill serialization, R2 evidence).
    (void)d_ws; (void)ws_size;

    vq_grid_kernel<<<GRID, BLK, 0, stream>>>(w, cb, y, out);
}

// Round 7
// 16.422 us; speedup vs baseline: 1.2631x; 1.2631x over previous
//
#include <hip/hip_runtime.h>

// VQ argmin: for each weight w[i], indices[i] = argmin_k (w[i] - cb[k])^2,
// first-index tie-break (matches jnp.argmin).
//
// Evidence ledger:
//  - ONE launch only: per-launch floor ~14-16 us, launches don't pipeline
//    (R0 42/1L, R3 16.3/1L, R4 44.6/3L).
//  - d_ws untouchable: 256 MiB poison-fill (~39 us) serializes into the
//    timed path when ws is used (R2).
//  - Fixed-grid buckets regressed twice (R5 20.7, R6 20.7) vs dynamic-range
//    buckets (R3 16.3): fixed grids put tail weights in EMPTY buckets ->
//    long ring-walks with best=+inf (no prune possible); dynamic range
//    clamps them into the extreme non-empty bucket.
// => This is R3's measured-best kernel verbatim, with exactly one change:
//    the serial t==0 min/max reduce (16-iter LDS loop stalling all 16
//    waves) is replaced by a parallel 32-lane shfl reduce.
//
// Exactness (identical semantics to the R3 run that passed absmax 0.0):
//  - dist computed exactly as reference: fl(fl(x-c)^2); fl monotone in |x-c|.
//  - Prune edges carry ONE FULL BUCKET of slack (>> any ulp slop in fp
//    bucket assignment) and prune only on fl(gap^2) > best STRICTLY -> no
//    entry tied at the final minimum is ever skipped.
//  - Surviving candidates compared with explicit (d, original_index)
//    lexicographic order -> atomic scatter order inside a bucket is
//    irrelevant; jnp.argmin first-index tie-break reproduced exactly.
//  - best starts +inf: pruning cannot fire before a real candidate is seen.
//  - NaN x: nothing accepted, prune never fires, sentinel -> 0, matching
//    np.argmin on an all-NaN row.
//  - Degenerate codebook (range <= 0): everything in bucket 0 == query
//    bucket, full exact scan, ring loop disabled.

#define N_W  262144
#define K_CB 1024
#define NB   256
#define BLK  1024
#define GRID (N_W / BLK)   // 256 blocks

__device__ __forceinline__ float dsq(float x, float c) {
    // Must match reference numerics exactly: subtract then square, fp32 RN.
    float d = x - c;
    return d * d;
}

__global__ __launch_bounds__(BLK) void vq_bucket_kernel(
    const float* __restrict__ w,
    const float* __restrict__ cb,
    const int* __restrict__ y,
    int* __restrict__ out)
{
    __shared__ float bval[K_CB];     // bucketed codebook values
    __shared__ int   bidx[K_CB];     // their original indices
    __shared__ int   hist[NB];
    __shared__ int   bstart[NB + 1]; // exclusive prefix (bucket ranges)
    __shared__ int   cursor[NB];     // scatter cursors
    __shared__ float wred[32];       // 16 wave-mins + 16 wave-maxs
    __shared__ float gmm[2];         // block min/max

    const int t    = threadIdx.x;
    const int gid  = blockIdx.x * BLK + t;   // grid covers N_W exactly
    const int lane = t & 63;
    const int wid  = t >> 6;

    float x = w[gid];    // issue both global loads up front
    float c = cb[t];     // K_CB == BLK: one entry per thread

    // ---- block min/max of codebook ----
    float m = c, M = c;
    #pragma unroll
    for (int off = 32; off >= 1; off >>= 1) {
        m = fminf(m, __shfl_xor(m, off));
        M = fmaxf(M, __shfl_xor(M, off));
    }
    if (lane == 0) { wred[wid] = m; wred[16 + wid] = M; }
    if (t < NB) hist[t] = 0;
    __syncthreads();                                   // B1

    // Parallel cross-wave reduce (replaces R3's serial t==0 16-iter loop):
    // lanes 0..15 reduce the 16 wave-mins, lanes 16..31 the 16 wave-maxs.
    if (t < 32) {
        float v = wred[t];
        #pragma unroll
        for (int off = 8; off >= 1; off >>= 1) {
            float o = __shfl_xor(v, off);      // partners stay within group
            v = (t < 16) ? fminf(v, o) : fmaxf(v, o);
        }
        if (t == 0)  gmm[0] = v;
        if (t == 16) gmm[1] = v;
    }
    __syncthreads();                                   // B2
    const float gmin  = gmm[0], gmax = gmm[1];
    const float range = gmax - gmin;
    const bool  degen = !(range > 0.0f);
    const float inv   = degen ? 0.0f : ((float)NB / range);
    const float width = degen ? 0.0f : (range / (float)NB);

    // ---- histogram ----
    int cbb = (int)((c - gmin) * inv);        // c-gmin >= 0 exactly
    cbb = min(max(cbb, 0), NB - 1);
    atomicAdd(&hist[cbb], 1);
    __syncthreads();                                   // B3

    // ---- exclusive prefix over 256 buckets (wave 0, shfl scan) ----
    if (wid == 0) {
        int h0 = hist[4 * lane + 0], h1 = hist[4 * lane + 1];
        int h2 = hist[4 * lane + 2], h3 = hist[4 * lane + 3];
        int s1 = h0 + h1, s2 = s1 + h2, tot = s2 + h3;
        int inc = tot;
        #pragma unroll
        for (int off = 1; off < 64; off <<= 1) {
            int v = __shfl_up(inc, off);
            if (lane >= off) inc += v;
        }
        int exc = inc - tot;
        bstart[4 * lane + 0] = exc;       cursor[4 * lane + 0] = exc;
        bstart[4 * lane + 1] = exc + h0;  cursor[4 * lane + 1] = exc + h0;
        bstart[4 * lane + 2] = exc + s1;  cursor[4 * lane + 2] = exc + s1;
        bstart[4 * lane + 3] = exc + s2;  cursor[4 * lane + 3] = exc + s2;
        if (lane == 63) bstart[NB] = inc; // == K_CB
    }
    __syncthreads();                                   // B4

    // ---- scatter (value, original index) into bucket slots ----
    int pos = atomicAdd(&cursor[cbb], 1);
    bval[pos] = c;
    bidx[pos] = t;
    __syncthreads();                                   // B5

    // ---- query: nearest codebook value to x ----
    int b = (int)((x - gmin) * inv);
    b = min(max(b, 0), NB - 1);

    float best = __builtin_inff();
    int   bi   = 0x7fffffff;

    {   // own bucket
        int e = bstart[b + 1];
        for (int i = bstart[b]; i < e; ++i) {
            float d = dsq(x, bval[i]);
            int idx = bidx[i];
            if (d < best)                   { best = d; bi = idx; }
            else if (d == best && idx < bi) { bi = idx; }
        }
    }

    int  dl = b - 1, dr = b + 1;
    bool goL = !degen && (dl >= 0);
    bool goR = !degen && (dr < NB);
    while (goL || goR) {
        if (goL) {
            // conservative upper edge of bucket dl (one bucket of slack)
            float edge = gmin + (float)(dl + 2) * width;
            float gap  = x - edge;
            if (gap > 0.0f && gap * gap > best) {
                goL = false;
            } else {
                int e = bstart[dl + 1];
                for (int i = bstart[dl]; i < e; ++i) {
                    float d = dsq(x, bval[i]);
                    int idx = bidx[i];
                    if (d < best)                   { best = d; bi = idx; }
                    else if (d == best && idx < bi) { bi = idx; }
                }
                if (--dl < 0) goL = false;
            }
        }
        if (goR) {
            // conservative lower edge of bucket dr (one bucket of slack)
            float edge = gmin + (float)(dr - 1) * width;
            float gap  = edge - x;
            if (gap > 0.0f && gap * gap > best) {
                goR = false;
            } else {
                int e = bstart[dr + 1];
                for (int i = bstart[dr]; i < e; ++i) {
                    float d = dsq(x, bval[i]);
                    int idx = bidx[i];
                    if (d < best)                   { best = d; bi = idx; }
                    else if (d == best && idx < bi) { bi = idx; }
                }
                if (++dr >= NB) goR = false;
            }
        }
    }
    if (bi == 0x7fffffff) bi = 0;   // NaN-x: matches np.argmin on all-NaN row
    out[gid] = bi;

    if (gid == 0) out[N_W] = y[0];
}

extern "C" void kernel_launch(void* const* d_in, const int* in_sizes, int n_in,
                              void* d_out, int out_size, void* d_ws, size_t ws_size,
                              hipStream_t stream) {
    const float* w  = (const float*)d_in[0];
    const float* cb = (const float*)d_in[1]; // (K,1) contiguous == K floats
    const int*   y  = (const int*)d_in[2];
    int* out = (int*)d_out;

    // ONE launch (per-launch overhead ~14-16 us, launches don't pipeline);
    // d_ws untouched (poison-fill serialization, R2 evidence).
    (void)d_ws; (void)ws_size;

    vq_bucket_kernel<<<GRID, BLK, 0, stream>>>(w, cb, y, out);
}